// Round 2
// baseline (385.721 us; speedup 1.0000x reference)
//
#include <hip/hip_runtime.h>
#include <math.h>

#define N_PTS 32768
#define MM 64
#define DD 8
#define OO 4
#define HH 4
#define NPAIR 16
#define JITTERV 1e-4

// workspace layout per pair (floats)
#define ES_OFF 0
#define W_OFF 4096
#define ZT_OFF (4096 + 64)
#define CC_OFF (ZT_OFF + 512)
#define INV2_OFF (CC_OFF + 64)
#define VAR_OFF (INV2_OFF + 8)
#define PAIR_STRIDE 4752   // multiple of 4 -> 16B alignment preserved

// ---------------- Phase 1: per-(h,o) small linear algebra in f64 ----------------
__global__ __launch_bounds__(256) void setup_kernel(
    const float* __restrict__ z, const float* __restrict__ u_mean,
    const float* __restrict__ utv, const float* __restrict__ log_ls,
    const float* __restrict__ log_var, float* __restrict__ ws)
{
    int p = blockIdx.x;
    int h = p / OO, o = p % OO;
    int tid = threadIdx.x;

    __shared__ double A[64][64];   // kuu -> in-place Cholesky (lower = L)
    __shared__ double Mi[64][64];  // L^{-1} (upper zeroed)
    __shared__ double Pm[64][64];  // LKinvLs^T * Mi
    __shared__ double Us[64][64];  // u_tril[i][a] / L[i][i]
    __shared__ double zs[64][8];
    __shared__ double ils[8];
    __shared__ double yv[64];
    __shared__ double dg[64];
    __shared__ double idg[64];

    const float* ll = log_ls + (h * OO + o) * DD;
    double lv = (double)log_var[h * OO + o];
    double var = exp(lv);

    if (tid < DD) ils[tid] = exp(-(double)ll[tid]);
    __syncthreads();

    if (tid < 64) {
        int m = tid;
        for (int d = 0; d < DD; ++d)
            zs[m][d] = (double)z[(o * MM + m) * DD + d] * ils[d];
    }
    __syncthreads();

    // kuu + jitter
    {
        int i = tid & 63, jq = tid >> 6;
        for (int j = jq * 16; j < jq * 16 + 16; ++j) {
            double s = 0;
            for (int d = 0; d < DD; ++d) { double df = zs[i][d] - zs[j][d]; s += df * df; }
            A[i][j] = var * exp(-0.5 * s) + ((i == j) ? (double)JITTERV : 0.0);
        }
    }
    __syncthreads();

    // Cholesky (lower), row-parallel right-looking
    for (int k = 0; k < 64; ++k) {
        if (tid == k) A[k][k] = sqrt(A[k][k]);
        __syncthreads();
        if (tid < 64 && tid > k) A[tid][k] /= A[k][k];
        __syncthreads();
        if (tid < 64 && tid > k) {
            double lik = A[tid][k];
            for (int j = k + 1; j <= tid; ++j) A[tid][j] -= lik * A[j][k];
        }
        __syncthreads();
    }
    if (tid < 64) { dg[tid] = A[tid][tid]; idg[tid] = 1.0 / A[tid][tid]; }
    __syncthreads();

    // Us[i][a] = u_tril[i][a] / L[i][i]  (zeros above diagonal)
    {
        const float* uo = utv + o * (MM * (MM + 1) / 2);
        for (int e = tid; e < 64 * 64; e += 256) {
            int i = e >> 6, a = e & 63;
            Us[i][a] = (a <= i) ? (double)uo[i * (i + 1) / 2 + a] * idg[i] : 0.0;
        }
    }

    // Mi = L^{-1}, thread = column j
    if (tid < 64) {
        int j = tid;
        for (int i = 0; i < j; ++i) Mi[i][j] = 0.0;
        Mi[j][j] = idg[j];
        for (int i = j + 1; i < 64; ++i) {
            double s = 0;
            for (int t = j; t < i; ++t) s += A[i][t] * Mi[t][j];
            Mi[i][j] = -s * idg[i];
        }
    }
    __syncthreads();

    // Pm[a][b] = sum_{i>=max(a,b)} Us[i][a] * Mi[i][b]
    {
        int b = tid & 63, aq = tid >> 6;
        for (int a = aq * 16; a < aq * 16 + 16; ++a) {
            int lo = a > b ? a : b;
            double s = 0;
            for (int i = lo; i < 64; ++i) s += Us[i][a] * Mi[i][b];
            Pm[a][b] = s;
        }
    }
    // yv = Mi * u_mean
    if (tid < 64) {
        int i = tid; double s = 0;
        for (int t = 0; t <= i; ++t) s += Mi[i][t] * (double)u_mean[o * MM + t];
        yv[i] = s;
    }
    __syncthreads();

    float* wsp = ws + (size_t)p * PAIR_STRIDE;

    // w[r] = sum_{i>=r} Mi[i][r] * yv[i]   (w = Kuu^{-1} u)
    if (tid < 64) {
        int r = tid; double s = 0;
        for (int i = r; i < 64; ++i) s += Mi[i][r] * yv[i];
        wsp[W_OFF + r] = (float)s;
    }

    // E = Pm^T Pm - Mi^T Mi ; store upper triangle with half-diagonal, zeros below
    {
        int c = tid & 63, rq = tid >> 6;
        for (int r = rq * 16; r < rq * 16 + 16; ++r) {
            double s = 0;
            for (int t = 0; t < 64; ++t) s += Pm[t][r] * Pm[t][c] - Mi[t][r] * Mi[t][c];
            float v;
            if (c < r) v = 0.f;
            else if (c == r) v = (float)(0.5 * s);
            else v = (float)s;
            wsp[ES_OFF + r * 64 + c] = v;
        }
    }

    // zt[m][d] = z*ls^-2 ; cc[m] = log_var - 0.5*B_m ; inv2 ; var
    if (tid < 64) {
        int m = tid;
        double B = 0;
        for (int d = 0; d < DD; ++d) {
            double zv = (double)z[(o * MM + m) * DD + d];
            double zt = zv * ils[d] * ils[d];
            wsp[ZT_OFF + m * DD + d] = (float)zt;
            B += zv * zt;
        }
        wsp[CC_OFF + m] = (float)(lv - 0.5 * B);
    }
    if (tid < DD) wsp[INV2_OFF + tid] = (float)(ils[tid] * ils[tid]);
    if (tid == 0) wsp[VAR_OFF] = (float)var;
}

// ---------------- Phase 2: streaming per-point evaluation ----------------
__global__ __launch_bounds__(256) void predict_kernel(
    const float* __restrict__ x, const float* __restrict__ ws,
    float* __restrict__ out)
{
    const int p = blockIdx.y;
    const float* __restrict__ wsp = ws + (size_t)p * PAIR_STRIDE;
    const float* __restrict__ Es  = wsp + ES_OFF;

    __shared__ float s_zt[512];
    __shared__ float s_cc[64];
    __shared__ float s_wv[64];
    __shared__ float s_iv2[8];
    __shared__ float s_var;

    const int tid = threadIdx.x;
    s_zt[tid] = wsp[ZT_OFF + tid];
    s_zt[tid + 256] = wsp[ZT_OFF + tid + 256];
    if (tid < 64) { s_cc[tid] = wsp[CC_OFF + tid]; s_wv[tid] = wsp[W_OFF + tid]; }
    if (tid < 8) s_iv2[tid] = wsp[INV2_OFF + tid];
    if (tid == 0) s_var = wsp[VAR_OFF];
    __syncthreads();

    const int n = blockIdx.x * 256 + tid;

    float4 xa = *(const float4*)(x + n * 8);
    float4 xb = *(const float4*)(x + n * 8 + 4);
    float xd[8] = {xa.x, xa.y, xa.z, xa.w, xb.x, xb.y, xb.z, xb.w};

    float Aq = 0.f;
    #pragma unroll
    for (int d = 0; d < 8; ++d) Aq = fmaf(xd[d] * xd[d], s_iv2[d], Aq);
    const float a0 = -0.5f * Aq;

    float k[64];
    #pragma unroll
    for (int m = 0; m < 64; ++m) {
        float s = s_cc[m] + a0;
        #pragma unroll
        for (int d = 0; d < 8; ++d) s = fmaf(xd[d], s_zt[m * 8 + d], s);
        k[m] = __expf(s);
    }

    float mu = 0.f;
    #pragma unroll
    for (int m = 0; m < 64; ++m) mu = fmaf(k[m], s_wv[m], mu);

    // pred_var = var + 2 * k^T E_upper k   (E stored with half-diagonal)
    float acc = 0.f;
    #pragma unroll
    for (int i = 0; i < 64; ++i) {
        float s = 0.f;
        #pragma unroll
        for (int j = (i & ~3); j < 64; j += 4) {
            float4 e = *(const float4*)(Es + i * 64 + j);
            s = fmaf(e.x, k[j], s);
            s = fmaf(e.y, k[j + 1], s);
            s = fmaf(e.z, k[j + 2], s);
            s = fmaf(e.w, k[j + 3], s);
        }
        acc = fmaf(k[i], s, acc);
    }

    out[p * N_PTS + n] = mu;
    out[NPAIR * N_PTS + p * N_PTS + n] = s_var + 2.0f * acc;
}

extern "C" void kernel_launch(void* const* d_in, const int* in_sizes, int n_in,
                              void* d_out, int out_size, void* d_ws, size_t ws_size,
                              hipStream_t stream) {
    const float* x   = (const float*)d_in[0];
    const float* z   = (const float*)d_in[1];
    const float* um  = (const float*)d_in[2];
    const float* utv = (const float*)d_in[3];
    const float* lls = (const float*)d_in[4];
    const float* lvr = (const float*)d_in[5];
    float* ws = (float*)d_ws;
    float* out = (float*)d_out;

    setup_kernel<<<16, 256, 0, stream>>>(z, um, utv, lls, lvr, ws);
    predict_kernel<<<dim3(N_PTS / 256, NPAIR), 256, 0, stream>>>(x, ws, out);
}

// Round 4
// 340.847 us; speedup vs baseline: 1.1317x; 1.1317x over previous
//
#include <hip/hip_runtime.h>
#include <math.h>

#define N_PTS 32768
#define MM 64
#define DD 8
#define OO 4
#define HH 4
#define NPAIR 16
#define JITTERV 1e-4
#define LOG2E 1.4426950408889634

// workspace layout per pair (floats)
#define ES_OFF 0
#define W_OFF 4096
#define ZT_OFF (4096 + 64)
#define CC_OFF (ZT_OFF + 512)
#define INV2_OFF (CC_OFF + 64)
#define VAR_OFF (INV2_OFF + 8)
#define PAIR_STRIDE 4752   // multiple of 4 -> 16B alignment preserved

// ---------------- Phase 1: per-(h,o) small linear algebra in f64 ----------------
// LDS arrays padded to stride 65: row stride 520B -> bank stride 2, kills the
// 64-way column-access conflicts (was 1.35M SQ_LDS_BANK_CONFLICT at stride 64).
__global__ __launch_bounds__(256) void setup_kernel(
    const float* __restrict__ z, const float* __restrict__ u_mean,
    const float* __restrict__ utv, const float* __restrict__ log_ls,
    const float* __restrict__ log_var, float* __restrict__ ws)
{
    int p = blockIdx.x;
    int h = p / OO, o = p % OO;
    int tid = threadIdx.x;

    __shared__ double A[64][65];   // kuu -> in-place Cholesky (lower = L)
    __shared__ double Mi[64][65];  // L^{-1} (upper zeroed)
    __shared__ double Pm[64][65];  // Us^T * Mi
    __shared__ double Us[64][65];  // u_tril[i][a] / L[i][i]
    __shared__ double zs[64][9];
    __shared__ double ils[8];
    __shared__ double yv[64];
    __shared__ double dg[64];
    __shared__ double idg[64];

    const float* ll = log_ls + (h * OO + o) * DD;
    double lv = (double)log_var[h * OO + o];
    double var = exp(lv);

    if (tid < DD) ils[tid] = exp(-(double)ll[tid]);
    __syncthreads();

    if (tid < 64) {
        int m = tid;
        for (int d = 0; d < DD; ++d)
            zs[m][d] = (double)z[(o * MM + m) * DD + d] * ils[d];
    }
    __syncthreads();

    // kuu + jitter
    {
        int i = tid & 63, jq = tid >> 6;
        for (int j = jq * 16; j < jq * 16 + 16; ++j) {
            double s = 0;
            for (int d = 0; d < DD; ++d) { double df = zs[i][d] - zs[j][d]; s += df * df; }
            A[i][j] = var * exp(-0.5 * s) + ((i == j) ? (double)JITTERV : 0.0);
        }
    }
    __syncthreads();

    // Cholesky (lower), row-parallel right-looking; reciprocal broadcast
    for (int k = 0; k < 64; ++k) {
        if (tid == k) { double d = sqrt(A[k][k]); A[k][k] = d; dg[k] = d; idg[k] = 1.0 / d; }
        __syncthreads();
        if (tid < 64 && tid > k) A[tid][k] *= idg[k];
        __syncthreads();
        if (tid < 64 && tid > k) {
            double lik = A[tid][k];
            for (int j = k + 1; j <= tid; ++j) A[tid][j] -= lik * A[j][k];
        }
        __syncthreads();
    }
    __syncthreads();

    // Us[i][a] = u_tril[i][a] / L[i][i]  (zeros above diagonal)
    {
        const float* uo = utv + o * (MM * (MM + 1) / 2);
        for (int e = tid; e < 64 * 64; e += 256) {
            int i = e >> 6, a = e & 63;
            Us[i][a] = (a <= i) ? (double)uo[i * (i + 1) / 2 + a] * idg[i] : 0.0;
        }
    }

    // Mi = L^{-1}, thread = column j
    if (tid < 64) {
        int j = tid;
        for (int i = 0; i < j; ++i) Mi[i][j] = 0.0;
        Mi[j][j] = idg[j];
        for (int i = j + 1; i < 64; ++i) {
            double s = 0;
            for (int t = j; t < i; ++t) s += A[i][t] * Mi[t][j];
            Mi[i][j] = -s * idg[i];
        }
    }
    __syncthreads();

    // Pm[a][b] = sum_{i>=max(a,b)} Us[i][a] * Mi[i][b]
    {
        int b = tid & 63, aq = tid >> 6;
        for (int a = aq * 16; a < aq * 16 + 16; ++a) {
            int lo = a > b ? a : b;
            double s = 0;
            for (int i = lo; i < 64; ++i) s += Us[i][a] * Mi[i][b];
            Pm[a][b] = s;
        }
    }
    // yv = Mi * u_mean
    if (tid < 64) {
        int i = tid; double s = 0;
        for (int t = 0; t <= i; ++t) s += Mi[i][t] * (double)u_mean[o * MM + t];
        yv[i] = s;
    }
    __syncthreads();

    float* wsp = ws + (size_t)p * PAIR_STRIDE;

    // w[r] = sum_{i>=r} Mi[i][r] * yv[i]   (w = Kuu^{-1} u)
    if (tid < 64) {
        int r = tid; double s = 0;
        for (int i = r; i < 64; ++i) s += Mi[i][r] * yv[i];
        wsp[W_OFF + r] = (float)s;
    }

    // E = Pm^T Pm - Mi^T Mi ; store upper triangle with half-diagonal, zeros below
    {
        int c = tid & 63, rq = tid >> 6;
        for (int r = rq * 16; r < rq * 16 + 16; ++r) {
            double s = 0;
            for (int t = 0; t < 64; ++t) s += Pm[t][r] * Pm[t][c] - Mi[t][r] * Mi[t][c];
            float v;
            if (c < r) v = 0.f;
            else if (c == r) v = (float)(0.5 * s);
            else v = (float)s;
            wsp[ES_OFF + r * 64 + c] = v;
        }
    }

    // zt[m][d] = z*ls^-2 * log2e ; cc[m] = (log_var - 0.5*B_m)*log2e ; iv2*log2e
    // (pre-scaled by log2(e) so predict uses native exp2)
    if (tid < 64) {
        int m = tid;
        double B = 0;
        for (int d = 0; d < DD; ++d) {
            double zv = (double)z[(o * MM + m) * DD + d];
            double zt = zv * ils[d] * ils[d];
            wsp[ZT_OFF + m * DD + d] = (float)(zt * LOG2E);
            B += zv * zt;
        }
        wsp[CC_OFF + m] = (float)((lv - 0.5 * B) * LOG2E);
    }
    if (tid < DD) wsp[INV2_OFF + tid] = (float)(ils[tid] * ils[tid] * LOG2E);
    if (tid == 0) wsp[VAR_OFF] = (float)var;
}

// ---------------- Phase 2: streaming per-point evaluation ----------------
__global__ __launch_bounds__(256) void predict_kernel(
    const float* __restrict__ x, const float* __restrict__ ws,
    float* __restrict__ out)
{
    const int p = blockIdx.y;
    const float* __restrict__ wsp = ws + (size_t)p * PAIR_STRIDE;

    __shared__ float s_Es[4096];   // 16 KB: E staged once, read as LDS broadcasts
    __shared__ float s_zt[512];
    __shared__ float s_cc[64];
    __shared__ float s_wv[64];
    __shared__ float s_iv2[8];
    __shared__ float s_var;

    const int tid = threadIdx.x;
    {
        const float4* __restrict__ Ev = (const float4*)(wsp + ES_OFF);
        float4* sv = (float4*)s_Es;
        #pragma unroll
        for (int e = 0; e < 4; ++e) sv[tid + e * 256] = Ev[tid + e * 256];
    }
    s_zt[tid] = wsp[ZT_OFF + tid];
    s_zt[tid + 256] = wsp[ZT_OFF + tid + 256];
    if (tid < 64) { s_cc[tid] = wsp[CC_OFF + tid]; s_wv[tid] = wsp[W_OFF + tid]; }
    if (tid < 8) s_iv2[tid] = wsp[INV2_OFF + tid];
    if (tid == 0) s_var = wsp[VAR_OFF];
    __syncthreads();

    const int n = blockIdx.x * 256 + tid;

    float4 xa = *(const float4*)(x + n * 8);
    float4 xb = *(const float4*)(x + n * 8 + 4);
    float xd[8] = {xa.x, xa.y, xa.z, xa.w, xb.x, xb.y, xb.z, xb.w};

    float Aq = 0.f;
    #pragma unroll
    for (int d = 0; d < 8; ++d) Aq = fmaf(xd[d] * xd[d], s_iv2[d], Aq);
    const float a0 = -0.5f * Aq;

    float k[64];
    #pragma unroll
    for (int m = 0; m < 64; ++m) {
        float s = s_cc[m] + a0;
        #pragma unroll
        for (int d = 0; d < 8; ++d) s = fmaf(xd[d], s_zt[m * 8 + d], s);
        k[m] = exp2f(s);
    }

    float mu = 0.f;
    #pragma unroll
    for (int m = 0; m < 64; ++m) mu = fmaf(k[m], s_wv[m], mu);

    // pred_var = var + 2 * k^T E_upper k   (E stored with half-diagonal)
    float acc = 0.f;
    #pragma unroll
    for (int i = 0; i < 64; ++i) {
        float s = 0.f;
        #pragma unroll
        for (int j = (i & ~3); j < 64; j += 4) {
            float4 e = *(const float4*)(s_Es + i * 64 + j);
            s = fmaf(e.x, k[j], s);
            s = fmaf(e.y, k[j + 1], s);
            s = fmaf(e.z, k[j + 2], s);
            s = fmaf(e.w, k[j + 3], s);
        }
        acc = fmaf(k[i], s, acc);
    }

    out[p * N_PTS + n] = mu;
    out[NPAIR * N_PTS + p * N_PTS + n] = s_var + 2.0f * acc;
}

extern "C" void kernel_launch(void* const* d_in, const int* in_sizes, int n_in,
                              void* d_out, int out_size, void* d_ws, size_t ws_size,
                              hipStream_t stream) {
    const float* x   = (const float*)d_in[0];
    const float* z   = (const float*)d_in[1];
    const float* um  = (const float*)d_in[2];
    const float* utv = (const float*)d_in[3];
    const float* lls = (const float*)d_in[4];
    const float* lvr = (const float*)d_in[5];
    float* ws = (float*)d_ws;
    float* out = (float*)d_out;

    setup_kernel<<<16, 256, 0, stream>>>(z, um, utv, lls, lvr, ws);
    predict_kernel<<<dim3(N_PTS / 256, NPAIR), 256, 0, stream>>>(x, ws, out);
}

// Round 6
// 245.263 us; speedup vs baseline: 1.5727x; 1.3897x over previous
//
#include <hip/hip_runtime.h>
#include <math.h>

#define N_PTS 32768
#define MM 64
#define DD 8
#define OO 4
#define HH 4
#define NPAIR 16
#define JITTERV 1e-4
#define LOG2E 1.4426950408889634

// workspace layout per pair (floats)
#define ES_OFF 0
#define W_OFF 4096
#define ZT_OFF (4096 + 64)
#define CC_OFF (ZT_OFF + 512)
#define INV2_OFF (CC_OFF + 64)
#define VAR_OFF (INV2_OFF + 8)
#define PAIR_STRIDE 4752   // multiple of 4 -> 16B alignment preserved

// ---------------- Phase 1: per-(h,o) small linear algebra in f64 ----------------
// Round-4 post-mortem: latency-bound (VALUBusy 0.5%), NOT conflict-bound.
// Runtime-trip-count loops (j<=tid, t<i) blocked unrolling -> ~130cy exposed
// LDS latency per iteration x ~4000 serial iters = 220us. This version makes
// every hot loop compile-time-bounded (predicated) so loads pipeline, and
// keeps the forward-substitution state in registers (lane = column).
__global__ __launch_bounds__(256) void setup_kernel(
    const float* __restrict__ z, const float* __restrict__ u_mean,
    const float* __restrict__ utv, const float* __restrict__ log_ls,
    const float* __restrict__ log_var, float* __restrict__ ws)
{
    const int p = blockIdx.x;
    const int h = p / OO, o = p % OO;
    const int tid = threadIdx.x;
    const int r = tid & 63;    // lane/row
    const int q = tid >> 6;    // wave quarter

    __shared__ double A[64][65];   // kuu -> lazy-scaled Cholesky -> L
    __shared__ double Mi[64][65];  // L^{-1} (upper zero)
    __shared__ double Pm[64][65];  // Us^T * Mi
    __shared__ double Us[64][65];  // u_tril[i][a] / L[i][i]
    __shared__ double zsh[64][9];
    __shared__ double ils[8];
    __shared__ double piv[64];
    __shared__ double idg[64];
    __shared__ double yv[64];

    const float* ll = log_ls + (h * OO + o) * DD;
    const double lv = (double)log_var[h * OO + o];
    const double var = exp(lv);

    if (tid < DD) ils[tid] = exp(-(double)ll[tid]);
    __syncthreads();

    if (tid < 64) {
        #pragma unroll
        for (int d = 0; d < DD; ++d)
            zsh[tid][d] = (double)z[(o * MM + tid) * DD + d] * ils[d];
    }
    __syncthreads();

    // kuu + jitter: thread (r,q) fills cols q*16..q*16+15 of row r
    #pragma unroll
    for (int jj = 0; jj < 16; ++jj) {
        const int j = q * 16 + jj;
        double s = 0;
        #pragma unroll
        for (int d = 0; d < DD; ++d) { double df = zsh[r][d] - zsh[j][d]; s += df * df; }
        A[r][j] = var * exp(-0.5 * s) + ((r == j) ? (double)JITTERV : 0.0);
    }
    __syncthreads();

    // Lazy-scaled Cholesky: invariant A[r][j] = L_unit[r][j]*D_j, pivot A[k][k]=D_k.
    // One barrier per step; redundant per-thread rcp; unrolled predicated quarter.
    for (int k = 0; k < 64; ++k) {
        const double pk = A[k][k];       // broadcast
        const double ipk = 1.0 / pk;
        if (tid == 0) piv[k] = pk;
        const double cf = A[r][k] * ipk; // per-lane column read
        #pragma unroll
        for (int jj = 0; jj < 16; ++jj) {
            const int j = q * 16 + jj;
            if (j > k && j <= r) A[r][j] -= cf * A[j][k];
        }
        __syncthreads();
    }

    if (tid < 64) idg[tid] = 1.0 / sqrt(piv[tid]);
    __syncthreads();

    // scale to true L: L[r][j] = A_w[r][j] * idg[j]  (j<=r)
    #pragma unroll
    for (int jj = 0; jj < 16; ++jj) {
        const int j = q * 16 + jj;
        if (j <= r) A[r][j] *= idg[j];
    }
    // pre-zero all of Mi so full-range reduces see zeros for unwritten terms
    for (int e = tid; e < 64 * 64; e += 256) Mi[e >> 6][e & 63] = 0.0;
    __syncthreads();

    // Mi = L^{-1}: lane j owns column j in registers (all indices compile-time).
    if (tid < 64) {
        const int j = tid;
        double y[64];
        #pragma unroll
        for (int t = 0; t < 64; ++t) y[t] = (t == j) ? idg[j] : 0.0;
        #pragma unroll
        for (int i = 1; i < 64; ++i) {
            double s0 = 0, s1 = 0, s2 = 0, s3 = 0;
            #pragma unroll
            for (int t = 0; t < i; t += 4) {
                s0 += A[i][t] * y[t];
                if (t + 1 < i) s1 += A[i][t + 1] * y[t + 1];
                if (t + 2 < i) s2 += A[i][t + 2] * y[t + 2];
                if (t + 3 < i) s3 += A[i][t + 3] * y[t + 3];
            }
            const double yi = -idg[i] * ((s0 + s1) + (s2 + s3));
            y[i] = (i > j) ? yi : y[i];
        }
        #pragma unroll
        for (int i = 0; i < 64; ++i) Mi[i][j] = y[i];
    }

    // Us[i][a] = u_tril[i][a] / L[i][i]  (zeros above diagonal)
    {
        const float* uo = utv + o * (MM * (MM + 1) / 2);
        for (int e = tid; e < 64 * 64; e += 256) {
            const int i = e >> 6, a = e & 63;
            Us[i][a] = (a <= i) ? (double)uo[i * (i + 1) / 2 + a] * idg[i] : 0.0;
        }
    }
    __syncthreads();

    // yv = Mi * u_mean
    if (tid < 64) {
        double s0 = 0, s1 = 0;
        #pragma unroll 16
        for (int t = 0; t < 64; t += 2) {
            s0 += Mi[tid][t] * (double)u_mean[o * MM + t];
            s1 += Mi[tid][t + 1] * (double)u_mean[o * MM + t + 1];
        }
        yv[tid] = s0 + s1;
    }
    __syncthreads();

    float* wsp = ws + (size_t)p * PAIR_STRIDE;

    // w[r] = sum_i Mi[i][r] * yv[i]
    if (tid < 64) {
        double s0 = 0, s1 = 0;
        #pragma unroll 16
        for (int i = 0; i < 64; i += 2) {
            s0 += Mi[i][tid] * yv[i];
            s1 += Mi[i + 1][tid] * yv[i + 1];
        }
        wsp[W_OFF + tid] = (float)(s0 + s1);
    }

    // Pm[a][b] = sum_i Us[i][a] * Mi[i][b]  (zeros make full range exact)
    #pragma unroll
    for (int aa = 0; aa < 16; ++aa) {
        const int a = q * 16 + aa;
        double s0 = 0, s1 = 0;
        #pragma unroll 16
        for (int i = 0; i < 64; i += 2) {
            s0 += Us[i][a] * Mi[i][r];
            s1 += Us[i + 1][a] * Mi[i + 1][r];
        }
        Pm[a][r] = s0 + s1;
    }
    __syncthreads();

    // E = Pm^T Pm - Mi^T Mi ; upper triangle, half-diagonal, zeros below
    #pragma unroll
    for (int rr = 0; rr < 16; ++rr) {
        const int row = q * 16 + rr;
        double s0 = 0, s1 = 0;
        #pragma unroll 16
        for (int t = 0; t < 64; ++t) {
            s0 += Pm[t][row] * Pm[t][r];
            s1 += Mi[t][row] * Mi[t][r];
        }
        const double s = s0 - s1;
        float v;
        if (r < row) v = 0.f;
        else if (r == row) v = (float)(0.5 * s);
        else v = (float)s;
        wsp[ES_OFF + row * 64 + r] = v;
    }

    // zt = z*ls^-2*log2e ; cc = (log_var-0.5*B)*log2e ; iv2*log2e ; var
    if (tid < 64) {
        const int m = tid;
        double B = 0;
        #pragma unroll
        for (int d = 0; d < DD; ++d) {
            const double zv = (double)z[(o * MM + m) * DD + d];
            const double zt = zv * ils[d] * ils[d];
            wsp[ZT_OFF + m * DD + d] = (float)(zt * LOG2E);
            B += zv * zt;
        }
        wsp[CC_OFF + m] = (float)((lv - 0.5 * B) * LOG2E);
    }
    if (tid < DD) wsp[INV2_OFF + tid] = (float)(ils[tid] * ils[tid] * LOG2E);
    if (tid == 0) wsp[VAR_OFF] = (float)var;
}

// ---------------- Phase 2: streaming per-point evaluation (UNCHANGED) ----------------
__global__ __launch_bounds__(256) void predict_kernel(
    const float* __restrict__ x, const float* __restrict__ ws,
    float* __restrict__ out)
{
    const int p = blockIdx.y;
    const float* __restrict__ wsp = ws + (size_t)p * PAIR_STRIDE;

    __shared__ float s_Es[4096];   // 16 KB: E staged once, read as LDS broadcasts
    __shared__ float s_zt[512];
    __shared__ float s_cc[64];
    __shared__ float s_wv[64];
    __shared__ float s_iv2[8];
    __shared__ float s_var;

    const int tid = threadIdx.x;
    {
        const float4* __restrict__ Ev = (const float4*)(wsp + ES_OFF);
        float4* sv = (float4*)s_Es;
        #pragma unroll
        for (int e = 0; e < 4; ++e) sv[tid + e * 256] = Ev[tid + e * 256];
    }
    s_zt[tid] = wsp[ZT_OFF + tid];
    s_zt[tid + 256] = wsp[ZT_OFF + tid + 256];
    if (tid < 64) { s_cc[tid] = wsp[CC_OFF + tid]; s_wv[tid] = wsp[W_OFF + tid]; }
    if (tid < 8) s_iv2[tid] = wsp[INV2_OFF + tid];
    if (tid == 0) s_var = wsp[VAR_OFF];
    __syncthreads();

    const int n = blockIdx.x * 256 + tid;

    float4 xa = *(const float4*)(x + n * 8);
    float4 xb = *(const float4*)(x + n * 8 + 4);
    float xd[8] = {xa.x, xa.y, xa.z, xa.w, xb.x, xb.y, xb.z, xb.w};

    float Aq = 0.f;
    #pragma unroll
    for (int d = 0; d < 8; ++d) Aq = fmaf(xd[d] * xd[d], s_iv2[d], Aq);
    const float a0 = -0.5f * Aq;

    float k[64];
    #pragma unroll
    for (int m = 0; m < 64; ++m) {
        float s = s_cc[m] + a0;
        #pragma unroll
        for (int d = 0; d < 8; ++d) s = fmaf(xd[d], s_zt[m * 8 + d], s);
        k[m] = exp2f(s);
    }

    float mu = 0.f;
    #pragma unroll
    for (int m = 0; m < 64; ++m) mu = fmaf(k[m], s_wv[m], mu);

    // pred_var = var + 2 * k^T E_upper k   (E stored with half-diagonal)
    float acc = 0.f;
    #pragma unroll
    for (int i = 0; i < 64; ++i) {
        float s = 0.f;
        #pragma unroll
        for (int j = (i & ~3); j < 64; j += 4) {
            float4 e = *(const float4*)(s_Es + i * 64 + j);
            s = fmaf(e.x, k[j], s);
            s = fmaf(e.y, k[j + 1], s);
            s = fmaf(e.z, k[j + 2], s);
            s = fmaf(e.w, k[j + 3], s);
        }
        acc = fmaf(k[i], s, acc);
    }

    out[p * N_PTS + n] = mu;
    out[NPAIR * N_PTS + p * N_PTS + n] = s_var + 2.0f * acc;
}

extern "C" void kernel_launch(void* const* d_in, const int* in_sizes, int n_in,
                              void* d_out, int out_size, void* d_ws, size_t ws_size,
                              hipStream_t stream) {
    const float* x   = (const float*)d_in[0];
    const float* z   = (const float*)d_in[1];
    const float* um  = (const float*)d_in[2];
    const float* utv = (const float*)d_in[3];
    const float* lls = (const float*)d_in[4];
    const float* lvr = (const float*)d_in[5];
    float* ws = (float*)d_ws;
    float* out = (float*)d_out;

    setup_kernel<<<16, 256, 0, stream>>>(z, um, utv, lls, lvr, ws);
    predict_kernel<<<dim3(N_PTS / 256, NPAIR), 256, 0, stream>>>(x, ws, out);
}

// Round 12
// 211.649 us; speedup vs baseline: 1.8225x; 1.1588x over previous
//
#include <hip/hip_runtime.h>
#include <math.h>

#define N_PTS 32768
#define MM 64
#define DD 8
#define OO 4
#define HH 4
#define NPAIR 16
#define JITTERV 1e-4
#define LOG2E 1.4426950408889634

// f32 workspace layout per pair
#define ES_OFF 0
#define W_OFF 4096
#define ZT_OFF (4096 + 64)
#define CC_OFF (ZT_OFF + 512)
#define INV2_OFF (CC_OFF + 64)
#define VAR_OFF (INV2_OFF + 8)
#define PAIR_STRIDE 4752
// f64 region (doubles), after the f32 region: 16*4752 floats = 38016 doubles
#define F64_BASE_D 38016
#define PMMI_STRIDE_D 8192   // per pair: Pm[4096] then Mi[4096]

// ---------------- Phase 1a: Cholesky + blocked inverse + Pm (16 blocks) ----------------
__global__ __launch_bounds__(256) void setup_chol(
    const float* __restrict__ z, const float* __restrict__ u_mean,
    const float* __restrict__ utv, const float* __restrict__ log_ls,
    const float* __restrict__ log_var, float* __restrict__ ws)
{
    const int p = blockIdx.x;
    const int h = p / OO, o = p % OO;
    const int tid = threadIdx.x;
    const int r = tid & 63;    // lane/row
    const int q = tid >> 6;    // wave quarter

    __shared__ double A[64][65];   // kuu -> lazy Cholesky -> true L
    __shared__ double Mi[64][65];  // L^{-1}
    __shared__ double Us[64][65];  // W-scratch during levels; then u_tril/diag
    __shared__ double zsh[64][9];
    __shared__ double ils[8];
    __shared__ double piv[64];
    __shared__ double idg[64];
    __shared__ double yv[64];

    const float* ll = log_ls + (h * OO + o) * DD;
    const double lv = (double)log_var[h * OO + o];
    const double var = exp(lv);

    if (tid < DD) ils[tid] = exp(-(double)ll[tid]);
    __syncthreads();

    if (tid < 64) {
        #pragma unroll
        for (int d = 0; d < DD; ++d)
            zsh[tid][d] = (double)z[(o * MM + tid) * DD + d] * ils[d];
    }
    __syncthreads();

    // kuu + jitter
    #pragma unroll
    for (int jj = 0; jj < 16; ++jj) {
        const int j = q * 16 + jj;
        double s = 0;
        #pragma unroll
        for (int d = 0; d < DD; ++d) { double df = zsh[r][d] - zsh[j][d]; s += df * df; }
        A[r][j] = var * exp(-0.5 * s) + ((r == j) ? (double)JITTERV : 0.0);
    }
    __syncthreads();

    // Lazy-scaled Cholesky: A[r][j] = L_unit[r][j]*D_j, A[k][k]=D_k. 1 barrier/step.
    for (int k = 0; k < 64; ++k) {
        const double pk = A[k][k];
        const double ipk = 1.0 / pk;
        if (tid == 0) piv[k] = pk;
        const double cf = A[r][k] * ipk;
        #pragma unroll
        for (int jj = 0; jj < 16; ++jj) {
            const int j = q * 16 + jj;
            if (j > k && j <= r) A[r][j] -= cf * A[j][k];
        }
        __syncthreads();
    }

    if (tid < 64) idg[tid] = 1.0 / sqrt(piv[tid]);
    __syncthreads();

    // scale to true L; pre-zero Mi
    #pragma unroll
    for (int jj = 0; jj < 16; ++jj) {
        const int j = q * 16 + jj;
        if (j <= r) A[r][j] *= idg[j];
    }
    for (int e = tid; e < 64 * 64; e += 256) Mi[e >> 6][e & 63] = 0.0;
    __syncthreads();

    // Blocked inverse, step 1: invert the four 16x16 diagonal blocks.
    if (tid < 64) {
        const int b = tid >> 4, c = tid & 15;
        const int g0 = b * 16;
        double y[16];
        #pragma unroll
        for (int t = 0; t < 16; ++t) y[t] = (t == c) ? idg[g0 + c] : 0.0;
        #pragma unroll
        for (int i = 1; i < 16; ++i) {
            double s = 0;
            #pragma unroll
            for (int t = 0; t < i; ++t) s += A[g0 + i][g0 + t] * y[t];
            const double yi = -idg[g0 + i] * s;
            y[i] = (i > c) ? yi : y[i];
        }
        #pragma unroll
        for (int i = 0; i < 16; ++i) Mi[g0 + i][g0 + c] = y[i];
    }
    __syncthreads();

    // Step 2: off-diagonal blocks by superdiagonal level.
    {
        const int lr = tid >> 4, lc = tid & 15;   // 16x16 entry grid
        #pragma unroll
        for (int lev = 1; lev < 4; ++lev) {
            #pragma unroll
            for (int bb = 0; bb < 4 - lev; ++bb) {
                const int i = bb + lev, j = bb;
                double s = 0;
                #pragma unroll
                for (int k = j; k < i; ++k)
                    #pragma unroll
                    for (int t = 0; t < 16; ++t)
                        s += A[i * 16 + lr][k * 16 + t] * Mi[k * 16 + t][j * 16 + lc];
                Us[bb * 16 + lr][lc] = s;   // W scratch
            }
            __syncthreads();
            #pragma unroll
            for (int bb = 0; bb < 4 - lev; ++bb) {
                const int i = bb + lev, j = bb;
                double s = 0;
                #pragma unroll
                for (int t = 0; t < 16; ++t)
                    s += Mi[i * 16 + lr][i * 16 + t] * Us[bb * 16 + t][lc];
                Mi[i * 16 + lr][j * 16 + lc] = -s;
            }
            __syncthreads();
        }
    }

    // Real Us fill + yv (Mi complete)
    {
        const float* uo = utv + o * (MM * (MM + 1) / 2);
        for (int e = tid; e < 64 * 64; e += 256) {
            const int i = e >> 6, a = e & 63;
            Us[i][a] = (a <= i) ? (double)uo[i * (i + 1) / 2 + a] * idg[i] : 0.0;
        }
    }
    if (tid < 64) {
        double s0 = 0, s1 = 0;
        #pragma unroll 16
        for (int t = 0; t < 64; t += 2) {
            s0 += Mi[tid][t] * (double)u_mean[o * MM + t];
            s1 += Mi[tid][t + 1] * (double)u_mean[o * MM + t + 1];
        }
        yv[tid] = s0 + s1;
    }
    __syncthreads();

    float* wsp = ws + (size_t)p * PAIR_STRIDE;
    double* ws64 = (double*)ws;
    double* pm64 = ws64 + F64_BASE_D + (size_t)p * PMMI_STRIDE_D;
    double* mi64 = pm64 + 4096;

    // w[r] = sum_i Mi[i][r] * yv[i]
    if (tid < 64) {
        double s0 = 0, s1 = 0;
        #pragma unroll 16
        for (int i = 0; i < 64; i += 2) {
            s0 += Mi[i][tid] * yv[i];
            s1 += Mi[i + 1][tid] * yv[i + 1];
        }
        wsp[W_OFF + tid] = (float)(s0 + s1);
    }

    // Pm[a][b] = sum_i Us[i][a] * Mi[i][b] -> straight to ws (f64)
    #pragma unroll
    for (int aa = 0; aa < 16; ++aa) {
        const int a = q * 16 + aa;
        double s0 = 0, s1 = 0;
        #pragma unroll 16
        for (int i = 0; i < 64; i += 2) {
            s0 += Us[i][a] * Mi[i][r];
            s1 += Us[i + 1][a] * Mi[i + 1][r];
        }
        pm64[a * 64 + r] = s0 + s1;
    }
    // Mi -> ws (f64), coalesced
    for (int e = tid; e < 4096; e += 256) mi64[e] = Mi[e >> 6][e & 63];

    // zt/cc/iv2/var (pre-scaled by log2e for exp2 in predict)
    if (tid < 64) {
        const int m = tid;
        double B = 0;
        #pragma unroll
        for (int d = 0; d < DD; ++d) {
            const double zv = (double)z[(o * MM + m) * DD + d];
            const double zt = zv * ils[d] * ils[d];
            wsp[ZT_OFF + m * DD + d] = (float)(zt * LOG2E);
            B += zv * zt;
        }
        wsp[CC_OFF + m] = (float)((lv - 0.5 * B) * LOG2E);
    }
    if (tid < DD) wsp[INV2_OFF + tid] = (float)(ils[tid] * ils[tid] * LOG2E);
    if (tid == 0) wsp[VAR_OFF] = (float)var;
}

// ---------------- Phase 1b: E = Pm^T Pm - Mi^T Mi (64 blocks) ----------------
__global__ __launch_bounds__(256) void e_kernel(float* __restrict__ ws)
{
    const int p = blockIdx.y;
    const int cx = blockIdx.x;          // 16-row chunk
    const int tid = threadIdx.x;
    const int c = tid & 63, rr = tid >> 6;

    __shared__ double sPm[64][64];
    __shared__ double sMi[64][64];

    const double* ws64 = (const double*)ws;
    const double* pm64 = ws64 + F64_BASE_D + (size_t)p * PMMI_STRIDE_D;
    const double* mi64 = pm64 + 4096;

    {
        const double2* gp = (const double2*)pm64;
        const double2* gm = (const double2*)mi64;
        double2* sp = (double2*)&sPm[0][0];
        double2* sm = (double2*)&sMi[0][0];
        #pragma unroll
        for (int e = 0; e < 8; ++e) {
            sp[tid + e * 256] = gp[tid + e * 256];
            sm[tid + e * 256] = gm[tid + e * 256];
        }
    }
    __syncthreads();

    float* esp = ws + (size_t)p * PAIR_STRIDE + ES_OFF;

    #pragma unroll
    for (int ii = 0; ii < 4; ++ii) {
        const int row = cx * 16 + rr * 4 + ii;
        double s0 = 0, s1 = 0;
        #pragma unroll 16
        for (int t = 0; t < 64; ++t) {
            s0 += sPm[t][row] * sPm[t][c];
            s1 += sMi[t][row] * sMi[t][c];
        }
        const double s = s0 - s1;
        float v;
        if (c < row) v = 0.f;
        else if (c == row) v = (float)(0.5 * s);
        else v = (float)s;
        esp[row * 64 + c] = v;
    }
}

// ---------------- Phase 2: 2 points/thread, shared E/zt LDS reads ----------------
// r8 theory: predict was LDS-issue-bound (~670 ds_read/point vs 19us VALU floor).
// kA/kB in registers (all compile-time indices); each float4 E row read feeds
// both points (8 FMA/load); zt rows read as float4 shared by both points.
__global__ __launch_bounds__(256) void predict_kernel(
    const float* __restrict__ x, const float* __restrict__ ws,
    float* __restrict__ out)
{
    const int p = blockIdx.y;
    const float* __restrict__ wsp = ws + (size_t)p * PAIR_STRIDE;

    __shared__ float s_Es[4096];
    __shared__ float s_zt[512];
    __shared__ float s_cc[64];
    __shared__ float s_wv[64];
    __shared__ float s_iv2[8];
    __shared__ float s_var;

    const int tid = threadIdx.x;
    {
        const float4* __restrict__ Ev = (const float4*)(wsp + ES_OFF);
        float4* sv = (float4*)s_Es;
        #pragma unroll
        for (int e = 0; e < 4; ++e) sv[tid + e * 256] = Ev[tid + e * 256];
    }
    s_zt[tid] = wsp[ZT_OFF + tid];
    s_zt[tid + 256] = wsp[ZT_OFF + tid + 256];
    if (tid < 64) { s_cc[tid] = wsp[CC_OFF + tid]; s_wv[tid] = wsp[W_OFF + tid]; }
    if (tid < 8) s_iv2[tid] = wsp[INV2_OFF + tid];
    if (tid == 0) s_var = wsp[VAR_OFF];
    __syncthreads();

    const int nA = blockIdx.x * 512 + tid;
    const int nB = nA + 256;

    float4 xa = *(const float4*)(x + nA * 8);
    float4 xb = *(const float4*)(x + nA * 8 + 4);
    float xdA[8] = {xa.x, xa.y, xa.z, xa.w, xb.x, xb.y, xb.z, xb.w};
    float4 xc = *(const float4*)(x + nB * 8);
    float4 xe = *(const float4*)(x + nB * 8 + 4);
    float xdB[8] = {xc.x, xc.y, xc.z, xc.w, xe.x, xe.y, xe.z, xe.w};

    float iv[8];
    #pragma unroll
    for (int d = 0; d < 8; ++d) iv[d] = s_iv2[d];

    float AqA = 0.f, AqB = 0.f;
    #pragma unroll
    for (int d = 0; d < 8; ++d) {
        AqA = fmaf(xdA[d] * xdA[d], iv[d], AqA);
        AqB = fmaf(xdB[d] * xdB[d], iv[d], AqB);
    }
    const float a0A = -0.5f * AqA;
    const float a0B = -0.5f * AqB;

    float kA[64], kB[64];
    float muA = 0.f, muB = 0.f;
    #pragma unroll
    for (int m = 0; m < 64; ++m) {
        float4 z0 = *(const float4*)(s_zt + m * 8);
        float4 z1 = *(const float4*)(s_zt + m * 8 + 4);
        const float cc = s_cc[m];
        float sA = cc + a0A, sB = cc + a0B;
        sA = fmaf(xdA[0], z0.x, sA); sB = fmaf(xdB[0], z0.x, sB);
        sA = fmaf(xdA[1], z0.y, sA); sB = fmaf(xdB[1], z0.y, sB);
        sA = fmaf(xdA[2], z0.z, sA); sB = fmaf(xdB[2], z0.z, sB);
        sA = fmaf(xdA[3], z0.w, sA); sB = fmaf(xdB[3], z0.w, sB);
        sA = fmaf(xdA[4], z1.x, sA); sB = fmaf(xdB[4], z1.x, sB);
        sA = fmaf(xdA[5], z1.y, sA); sB = fmaf(xdB[5], z1.y, sB);
        sA = fmaf(xdA[6], z1.z, sA); sB = fmaf(xdB[6], z1.z, sB);
        sA = fmaf(xdA[7], z1.w, sA); sB = fmaf(xdB[7], z1.w, sB);
        kA[m] = exp2f(sA);
        kB[m] = exp2f(sB);
        const float wv = s_wv[m];
        muA = fmaf(kA[m], wv, muA);
        muB = fmaf(kB[m], wv, muB);
    }

    // pred_var = var + 2 * k^T E_upper k  (E stored with half-diagonal)
    float accA = 0.f, accB = 0.f;
    #pragma unroll
    for (int i = 0; i < 64; ++i) {
        float sA = 0.f, sB = 0.f;
        #pragma unroll
        for (int j = (i & ~3); j < 64; j += 4) {
            float4 e = *(const float4*)(s_Es + i * 64 + j);
            sA = fmaf(e.x, kA[j], sA);     sB = fmaf(e.x, kB[j], sB);
            sA = fmaf(e.y, kA[j + 1], sA); sB = fmaf(e.y, kB[j + 1], sB);
            sA = fmaf(e.z, kA[j + 2], sA); sB = fmaf(e.z, kB[j + 2], sB);
            sA = fmaf(e.w, kA[j + 3], sA); sB = fmaf(e.w, kB[j + 3], sB);
        }
        accA = fmaf(kA[i], sA, accA);
        accB = fmaf(kB[i], sB, accB);
    }

    const float varf = s_var;
    out[p * N_PTS + nA] = muA;
    out[p * N_PTS + nB] = muB;
    out[NPAIR * N_PTS + p * N_PTS + nA] = varf + 2.0f * accA;
    out[NPAIR * N_PTS + p * N_PTS + nB] = varf + 2.0f * accB;
}

extern "C" void kernel_launch(void* const* d_in, const int* in_sizes, int n_in,
                              void* d_out, int out_size, void* d_ws, size_t ws_size,
                              hipStream_t stream) {
    const float* x   = (const float*)d_in[0];
    const float* z   = (const float*)d_in[1];
    const float* um  = (const float*)d_in[2];
    const float* utv = (const float*)d_in[3];
    const float* lls = (const float*)d_in[4];
    const float* lvr = (const float*)d_in[5];
    float* ws = (float*)d_ws;
    float* out = (float*)d_out;

    setup_chol<<<16, 256, 0, stream>>>(z, um, utv, lls, lvr, ws);
    e_kernel<<<dim3(4, NPAIR), 256, 0, stream>>>(ws);
    predict_kernel<<<dim3(N_PTS / 512, NPAIR), 256, 0, stream>>>(x, ws, out);
}